// Round 5
// baseline (565772.412 us; speedup 1.0000x reference)
//
#include <hip/hip_runtime.h>
#include <stdint.h>

#define H   512
#define B   64
#define T   512
#define E   256
#define G3  1536   // 3*H
#define CT  64     // time-chunk length (T/CT = 8 chunks)

typedef unsigned short u16;

__device__ __forceinline__ float b2f(u16 u) {
    union { unsigned int i; float f; } v; v.i = ((unsigned int)u) << 16; return v.f;
}
__device__ __forceinline__ u16 f2b(float f) {
    union { float f; unsigned int i; } v; v.f = f;
    unsigned int r = v.i + 0x7FFF + ((v.i >> 16) & 1);
    return (u16)(r >> 16);
}
__device__ __forceinline__ float sigm(float x)  { return 1.f / (1.f + __expf(-x)); }
__device__ __forceinline__ float tanhs(float x) { return 1.f - 2.f / (1.f + __expf(2.f * x)); }
// dtype-adaptive element load: buffer is fp32 if isf32 else bf16
__device__ __forceinline__ float ldf(const void* p, long i, int isf32) {
    return isf32 ? ((const float*)p)[i] : b2f(((const u16*)p)[i]);
}

// ------------------------------------------------------- dtype detection
// Interpret first 65536 shorts of emb as bf16. True-bf16 emb (0.1*N(0,1))
// has max|x| ~ 0.6. If emb is fp32, half those shorts are mantissa words ->
// log-uniform garbage magnitudes (and NaNs) -> max explodes past 1e4.
__global__ void k_detect(const u16* __restrict__ emb_u16, int* __restrict__ flag) {
    __shared__ float red[256];
    float m = 0.f;
    for (int i = threadIdx.x; i < 65536; i += 256) {
        float v = b2f(emb_u16[i]);
        v = (v == v) ? fabsf(v) : 1e30f;       // NaN counts as huge
        m = fmaxf(m, v);
    }
    red[threadIdx.x] = m;
    __syncthreads();
    for (int o = 128; o > 0; o >>= 1) {
        if (threadIdx.x < o) red[threadIdx.x] = fmaxf(red[threadIdx.x], red[threadIdx.x + o]);
        __syncthreads();
    }
    if (threadIdx.x == 0) flag[0] = (red[0] > 1e4f) ? 1 : 0;
}

// ------------------------------------------------------- xg chunk GEMM (pure VALU)
// xg[d][m][n] = sum_k A[m][k] * Wih[d][n][k] + bih[d][n]
// m = b*CT + tl ; t = t0(d,c) + tl ; t0(0,c)=c*CT, t0(1,c)=T-(c+1)*CT
// Layer 0: A-row = emb[sent[b*T+t]] (dtype = flag). Layer 1: A-row = x1 (bf16, self-written).
__global__ __launch_bounds__(256)
void k_xg(const int* __restrict__ sent, const void* __restrict__ embOrX, int useEmb,
          const void* __restrict__ Wih, const void* __restrict__ bih,
          const int* __restrict__ flag, float* __restrict__ xg, int AK, int c) {
    int d   = blockIdx.z;
    int isf = flag[0];
    int m   = blockIdx.x;                          // 0..4095
    int n   = blockIdx.y * 256 + threadIdx.x;      // 0..1535
    int b   = m / CT, tl = m % CT;
    int t0  = d ? (T - (c + 1) * CT) : c * CT;
    int t   = t0 + tl;

    long arow;
    int  aIsF;
    if (useEmb) { arow = (long)sent[b * T + t] * AK;   aIsF = isf; }
    else        { arow = ((long)b * T + t) * AK;       aIsF = 0;   }

    long wrow = ((long)d * G3 + n) * AK;
    float acc = 0.f;
    for (int k = 0; k < AK; k++)
        acc += ldf(embOrX, arow + k, aIsF) * ldf(Wih, wrow + k, isf);

    xg[((long)d * B * CT + m) * G3 + n] = acc + ldf(bih, (long)d * G3 + n, isf);
}

// ------------------------------------------------------- zero h32
__global__ void k_zero(float* h32) {
    int i = blockIdx.x * 256 + threadIdx.x;        // 131072 = 2 dirs * 2 slices * B*H
    h32[i] = 0.f;
}

// ------------------------------------------------------- GRU step (pure VALU)
// grid (128, 2) x 256 threads. Wave wv of block x owns unit u = x*4+wv for all
// 64 batches (lane = batch). Three fp32 dot products over K=512.
__global__ __launch_bounds__(256)
void k_step(const void* __restrict__ Whh, const void* __restrict__ bhh,
            const int* __restrict__ flag, const float* __restrict__ xg,
            float* __restrict__ h32, int s, u16* __restrict__ x1out, int writeX1) {
    int d   = blockIdx.y;
    int isf = flag[0];
    int wv  = threadIdx.x >> 6;
    int b   = threadIdx.x & 63;
    int u   = blockIdx.x * 4 + wv;                 // 0..511

    long wbase = (long)d * G3 * H;
    const float* xgf = xg + (long)d * B * CT * G3;

    int time = d ? (T - 1 - s) : s;
    int sl   = s % CT;
    int tl   = d ? (CT - 1 - sl) : sl;

    const float* hprev = h32 + (long)(d * 2 + (s & 1)) * B * H;
    float*       hnew  = h32 + (long)(d * 2 + ((s + 1) & 1)) * B * H;

    const float* hrow = hprev + (long)b * H;
    long wr = wbase + (long)u * H;
    long wz = wbase + (long)(H + u) * H;
    long wn = wbase + (long)(2 * H + u) * H;

    float ar = 0.f, az = 0.f, an = 0.f;
    #pragma unroll 4
    for (int k = 0; k < H; k++) {
        float hk = hrow[k];
        ar += hk * ldf(Whh, wr + k, isf);
        az += hk * ldf(Whh, wz + k, isf);
        an += hk * ldf(Whh, wn + k, isf);
    }

    long bb    = (long)d * G3;
    long xbase = ((long)b * CT + tl) * G3;
    float r  = sigm(xgf[xbase + u]         + ar + ldf(bhh, bb + u,         isf));
    float z  = sigm(xgf[xbase + H + u]     + az + ldf(bhh, bb + H + u,     isf));
    float n  = tanhs(xgf[xbase + 2 * H + u] + r * (an + ldf(bhh, bb + 2 * H + u, isf)));
    float hp = hprev[(long)b * H + u];
    float hh = (1.f - z) * n + z * hp;

    hnew[(long)b * H + u] = hh;
    if (writeX1)
        x1out[((long)b * T + time) * 1024 + d * H + u] = f2b(hh);
}

// ------------------------------------------------------- final FC (adaptive output dtype)
__global__ __launch_bounds__(256)
void k_fc(const float* __restrict__ h32, const void* __restrict__ fcw,
          const void* __restrict__ fcb, const int* __restrict__ flag,
          void* __restrict__ out) {
    int b   = blockIdx.x;
    int tid = threadIdx.x;
    int isf = flag[0];
    float p[10];
    #pragma unroll
    for (int o = 0; o < 10; o++) p[o] = 0.f;
    for (int k = tid; k < 1024; k += 256) {
        int dd = k >> 9, kk = k & 511;
        // final h lives in ping-pong slice (T & 1) == 0 of each dir
        float hv = h32[(long)dd * 2 * B * H + (long)b * H + kk];
        #pragma unroll
        for (int o = 0; o < 10; o++) p[o] += hv * ldf(fcw, (long)o * 1024 + k, isf);
    }
    __shared__ float red[10][256];
    #pragma unroll
    for (int o = 0; o < 10; o++) red[o][tid] = p[o];
    __syncthreads();
    for (int off = 128; off > 0; off >>= 1) {
        if (tid < off)
            #pragma unroll
            for (int o = 0; o < 10; o++) red[o][tid] += red[o][tid + off];
        __syncthreads();
    }
    if (tid < 10) {
        float v = red[tid][0] + ldf(fcb, tid, isf);
        if (isf) ((float*)out)[b * 10 + tid] = v;
        else     ((u16*)out)[b * 10 + tid]   = f2b(v);
    }
}

// ------------------------------------------------------- launcher
extern "C" void kernel_launch(void* const* d_in, const int* in_sizes, int n_in,
                              void* d_out, int out_size, void* d_ws, size_t ws_size,
                              hipStream_t stream) {
    const int*  sent = (const int*)d_in[0];
    const void* emb  = d_in[1];
    const void* wih0 = d_in[2];
    const void* whh0 = d_in[3];
    const void* bih0 = d_in[4];
    const void* bhh0 = d_in[5];
    const void* wih1 = d_in[6];
    const void* whh1 = d_in[7];
    const void* bih1 = d_in[8];
    const void* bhh1 = d_in[9];
    const void* fcw  = d_in[10];
    const void* fcb  = d_in[11];

    // workspace layout (~118 MB — envelope proven safe in rounds 2-4)
    char*  ws   = (char*)d_ws;
    float* xg   = (float*)(ws);                          // 2*B*CT*G3*4 = 50,331,648 B
    u16*   x1   = (u16*)(ws + 50331648L);                // B*T*1024*2  = 67,108,864 B
    float* h32  = (float*)(ws + 50331648L + 67108864L);  // 2*2*B*H*4   =    524,288 B
    int*   flag = (int*)(ws + 50331648L + 67108864L + 524288L); // 256 B

    k_detect<<<1, 256, 0, stream>>>((const u16*)emb, flag);

    dim3 gg(B * CT, 6, 2);   // 4096 m-rows x 6 n-blocks x 2 dirs
    dim3 gs(128, 2);         // 128 unit-quads x 2 dirs

    // ---- layer 0 (embedding lookup fused into GEMM A-read) ----
    k_zero<<<512, 256, 0, stream>>>(h32);
    for (int c = 0; c < T / CT; c++) {
        k_xg<<<gg, 256, 0, stream>>>(sent, emb, 1, wih0, bih0, flag, xg, E, c);
        for (int s = c * CT; s < (c + 1) * CT; s++)
            k_step<<<gs, 256, 0, stream>>>(whh0, bhh0, flag, xg, h32, s, x1, 1);
    }

    // ---- layer 1 ----
    k_zero<<<512, 256, 0, stream>>>(h32);
    for (int c = 0; c < T / CT; c++) {
        k_xg<<<gg, 256, 0, stream>>>(sent, x1, 0, wih1, bih1, flag, xg, 2 * H, c);
        for (int s = c * CT; s < (c + 1) * CT; s++)
            k_step<<<gs, 256, 0, stream>>>(whh1, bhh1, flag, xg, h32, s, (u16*)nullptr, 0);
    }

    k_fc<<<B, 256, 0, stream>>>(h32, fcw, fcb, flag, d_out);
}

// Round 6
// 13690.393 us; speedup vs baseline: 41.3262x; 41.3262x over previous
//
#include <hip/hip_runtime.h>
#include <stdint.h>

#define H   512
#define B   64
#define T   512
#define E   256
#define G3  1536   // 3*H
#define CT  64     // time-chunk length (T/CT = 8 chunks)

typedef short s16;
typedef unsigned short u16;
typedef __attribute__((ext_vector_type(8))) short   short8;
typedef __attribute__((ext_vector_type(4))) float   f32x4;
typedef __attribute__((ext_vector_type(8))) float   f32x8;
typedef __bf16 bf8_t __attribute__((ext_vector_type(8)));

__device__ __forceinline__ u16 f2b(float f) {
    union { float f; unsigned int i; } v; v.f = f;
    unsigned int r = v.i + 0x7FFF + ((v.i >> 16) & 1);
    return (u16)(r >> 16);
}
__device__ __forceinline__ float b2f(u16 u) {
    union { unsigned int i; float f; } v; v.i = ((unsigned int)u) << 16; return v.f;
}
__device__ __forceinline__ float sigm(float x)  { return 1.f / (1.f + __expf(-x)); }
__device__ __forceinline__ float tanhs(float x) { return 1.f - 2.f / (1.f + __expf(2.f * x)); }

// ------------------------------------------------------- fp32 -> bf16 weight convert
__global__ void k_cvt(const float* __restrict__ src, u16* __restrict__ dst, int n) {
    int i = blockIdx.x * 256 + threadIdx.x;
    int stride = gridDim.x * 256;
    for (; i < n; i += stride) dst[i] = f2b(src[i]);
}

// ------------------------------------------------------- xg chunk GEMM (MFMA)
// xg[d][m][n] (fp32) = A[m,:K] . Wbf[d][n][:K] + bih[d][n]
// m = b*CT+tl, t = t0(d,c)+tl; t0(0,c)=c*CT, t0(1,c)=T-(c+1)*CT
// A: layer0 = emb fp32 gathered via sent (aIsF32=1); layer1 = x1 bf16 (aIsF32=0).
#define BM 128
#define BN 128
#define BK 32

__global__ __launch_bounds__(256)
void k_gemm_xg(const int* __restrict__ sent, const void* __restrict__ Abuf, int aIsF32,
               const u16* __restrict__ Wbf, const float* __restrict__ bih,
               float* __restrict__ xg, int K, int c) {
    int d  = blockIdx.z;
    int t0 = d ? (T - (c + 1) * CT) : c * CT;
    const u16* Bw = Wbf + (long)d * G3 * K;
    const float* bias = bih + (long)d * G3;
    float* C = xg + (long)d * (long)(B * CT) * G3;

    __shared__ __align__(16) s16 lA[BM * BK];
    __shared__ __align__(16) s16 lB[BN * BK];

    int tid  = threadIdx.x;
    int lane = tid & 63;
    int wv   = tid >> 6;
    int wm   = wv >> 1, wn = wv & 1;
    int q    = lane >> 4, r16 = lane & 15;

    long m0 = (long)blockIdx.x * BM;
    long n0 = (long)blockIdx.y * BN;

    // per-thread staging row pointers (2 chunks of 8 elems each)
    const float* rowAf[2];
    const s16*   rowAh[2];
    const u16*   rowB[2];
    #pragma unroll
    for (int i = 0; i < 2; i++) {
        int ch = tid + i * 256;
        int r  = ch >> 2, cc = (ch & 3) * 8;
        long m = m0 + r;
        int  bb_ = (int)(m >> 6), tl = (int)(m & 63);
        int  t  = t0 + tl;
        if (aIsF32) rowAf[i] = (const float*)Abuf + (long)sent[bb_ * T + t] * K + cc;
        else        rowAh[i] = (const s16*)Abuf + ((long)bb_ * T + t) * K + cc;
        rowB[i] = Bw + (n0 + r) * K + cc;
    }

    f32x4 acc[4][4];
    #pragma unroll
    for (int i = 0; i < 4; i++)
        #pragma unroll
        for (int j = 0; j < 4; j++) acc[i][j] = (f32x4){0.f, 0.f, 0.f, 0.f};

    for (long k0 = 0; k0 < K; k0 += BK) {
        #pragma unroll
        for (int i = 0; i < 2; i++) {
            if (aIsF32) {
                float4 v0 = *(const float4*)(rowAf[i] + k0);
                float4 v1 = *(const float4*)(rowAf[i] + k0 + 4);
                short8 pk;
                pk[0] = (s16)f2b(v0.x); pk[1] = (s16)f2b(v0.y);
                pk[2] = (s16)f2b(v0.z); pk[3] = (s16)f2b(v0.w);
                pk[4] = (s16)f2b(v1.x); pk[5] = (s16)f2b(v1.y);
                pk[6] = (s16)f2b(v1.z); pk[7] = (s16)f2b(v1.w);
                ((short8*)lA)[tid + i * 256] = pk;
            } else {
                ((short8*)lA)[tid + i * 256] = *(const short8*)(rowAh[i] + k0);
            }
            ((short8*)lB)[tid + i * 256] = *(const short8*)((const s16*)rowB[i] + k0);
        }
        __syncthreads();

        bf8_t af[4], bf[4];
        #pragma unroll
        for (int mt = 0; mt < 4; mt++)
            af[mt] = ((const bf8_t*)lA)[(wm * 64 + mt * 16 + r16) * 4 + q];
        #pragma unroll
        for (int nt = 0; nt < 4; nt++)
            bf[nt] = ((const bf8_t*)lB)[(wn * 64 + nt * 16 + r16) * 4 + q];
        #pragma unroll
        for (int mt = 0; mt < 4; mt++)
            #pragma unroll
            for (int nt = 0; nt < 4; nt++)
                acc[mt][nt] = __builtin_amdgcn_mfma_f32_16x16x32_bf16(
                                  af[mt], bf[nt], acc[mt][nt], 0, 0, 0);
        __syncthreads();
    }

    // D[m][n]: n = lane&15 (+tiles), m = (lane>>4)*4 + reg (+tiles)
    #pragma unroll
    for (int nt = 0; nt < 4; nt++) {
        long n = n0 + wn * 64 + nt * 16 + r16;
        float bv = bias[n];
        #pragma unroll
        for (int mt = 0; mt < 4; mt++) {
            #pragma unroll
            for (int rg = 0; rg < 4; rg++) {
                long m = m0 + wm * 64 + mt * 16 + q * 4 + rg;
                C[m * G3 + n] = acc[mt][nt][rg] + bv;
            }
        }
    }
}

// ------------------------------------------------------- zero h32
__global__ void k_zero(float* h32) {
    int i = blockIdx.x * 256 + threadIdx.x;      // 131072 = 2 dirs * 2 slices * B*H
    h32[i] = 0.f;
}

// ------------------------------------------------------- GRU step (MFMA)
// grid (32 unit-tiles, 2 dirs) x 256 threads (4 waves; wave g = batches g*16..+15).
// Lane (q,c): A-frag m=c (batch g*16+c), B-frag n=c (unit u0+c), k=kc*32+q*8+j.
// D: m=(lane>>4)*4+rg -> batch g*16+q*4+rg, n=c -> unit u0+c. 3 accumulators r/z/n.
__global__ __launch_bounds__(256)
void k_step(const u16* __restrict__ Whhbf, const float* __restrict__ bhh,
            const float* __restrict__ xg, float* __restrict__ h32, int s,
            u16* __restrict__ x1out, int writeX1) {
    int u0  = blockIdx.x * 16;
    int d   = blockIdx.y;
    int lane = threadIdx.x & 63;
    int g    = threadIdx.x >> 6;
    int q    = lane >> 4, c = lane & 15;

    const u16* W = Whhbf + (long)d * G3 * H;
    const float* bb = bhh + (long)d * G3;
    const float* xgf = xg + (long)d * (long)(B * CT) * G3;

    int time = d ? (T - 1 - s) : s;
    int sl   = s & (CT - 1);
    int tl   = d ? (CT - 1 - sl) : sl;

    const float* hprev = h32 + (long)(d * 2 + (s & 1)) * B * H;
    float*       hnew  = h32 + (long)(d * 2 + ((s + 1) & 1)) * B * H;

    f32x4 aR = (f32x4){0.f,0.f,0.f,0.f};
    f32x4 aZ = (f32x4){0.f,0.f,0.f,0.f};
    f32x4 aN = (f32x4){0.f,0.f,0.f,0.f};

    int bA = g * 16 + c;
    const float* hrow = hprev + (long)bA * H;

    #pragma unroll 4
    for (int kc = 0; kc < 16; kc++) {
        f32x8 hv = *(const f32x8*)(hrow + kc * 32 + q * 8);
        bf8_t af;
        #pragma unroll
        for (int j = 0; j < 8; j++) af[j] = (__bf16)hv[j];
        bf8_t wR = *(const bf8_t*)(W + (long)(0 * H + u0 + c) * H + kc * 32 + q * 8);
        bf8_t wZ = *(const bf8_t*)(W + (long)(1 * H + u0 + c) * H + kc * 32 + q * 8);
        bf8_t wN = *(const bf8_t*)(W + (long)(2 * H + u0 + c) * H + kc * 32 + q * 8);
        aR = __builtin_amdgcn_mfma_f32_16x16x32_bf16(af, wR, aR, 0, 0, 0);
        aZ = __builtin_amdgcn_mfma_f32_16x16x32_bf16(af, wZ, aZ, 0, 0, 0);
        aN = __builtin_amdgcn_mfma_f32_16x16x32_bf16(af, wN, aN, 0, 0, 0);
    }

    int u = u0 + c;
    float br = bb[u], bz = bb[H + u], bn = bb[2 * H + u];

    #pragma unroll
    for (int rg = 0; rg < 4; rg++) {
        int b = g * 16 + q * 4 + rg;
        long xbase = ((long)b * CT + tl) * G3;
        float r = sigm(xgf[xbase + u]          + aR[rg] + br);
        float z = sigm(xgf[xbase + H + u]      + aZ[rg] + bz);
        float n = tanhs(xgf[xbase + 2 * H + u] + r * (aN[rg] + bn));
        float hp = hprev[(long)b * H + u];
        float hh = (1.f - z) * n + z * hp;
        hnew[(long)b * H + u] = hh;
        if (writeX1)
            x1out[((long)b * T + time) * 1024 + d * H + u] = f2b(hh);
    }
}

// ------------------------------------------------------- final FC (fp32)
__global__ __launch_bounds__(256)
void k_fc(const float* __restrict__ h32, const float* __restrict__ fcw,
          const float* __restrict__ fcb, float* __restrict__ out) {
    int b   = blockIdx.x;
    int tid = threadIdx.x;
    float p[10];
    #pragma unroll
    for (int o = 0; o < 10; o++) p[o] = 0.f;
    for (int k = tid; k < 1024; k += 256) {
        int dd = k >> 9, kk = k & 511;
        // final h lives in ping-pong slice 0 of each dir (T even)
        float hv = h32[(long)dd * 2 * B * H + (long)b * H + kk];
        #pragma unroll
        for (int o = 0; o < 10; o++) p[o] += hv * fcw[o * 1024 + k];
    }
    __shared__ float red[10][256];
    #pragma unroll
    for (int o = 0; o < 10; o++) red[o][tid] = p[o];
    __syncthreads();
    for (int off = 128; off > 0; off >>= 1) {
        if (tid < off)
            #pragma unroll
            for (int o = 0; o < 10; o++) red[o][tid] += red[o][tid + off];
        __syncthreads();
    }
    if (tid < 10) out[b * 10 + tid] = red[tid][0] + fcb[tid];
}

// ------------------------------------------------------- launcher
extern "C" void kernel_launch(void* const* d_in, const int* in_sizes, int n_in,
                              void* d_out, int out_size, void* d_ws, size_t ws_size,
                              hipStream_t stream) {
    const int*   sent = (const int*)d_in[0];
    const float* emb  = (const float*)d_in[1];
    const float* wih0 = (const float*)d_in[2];
    const float* whh0 = (const float*)d_in[3];
    const float* bih0 = (const float*)d_in[4];
    const float* bhh0 = (const float*)d_in[5];
    const float* wih1 = (const float*)d_in[6];
    const float* whh1 = (const float*)d_in[7];
    const float* bih1 = (const float*)d_in[8];
    const float* bhh1 = (const float*)d_in[9];
    const float* fcw  = (const float*)d_in[10];
    const float* fcb  = (const float*)d_in[11];
    float* outp = (float*)d_out;

    // workspace layout — 132 MB total (proven-safe envelope: >=134.5 MB)
    char*  ws  = (char*)d_ws;
    float* xg  = (float*)(ws);                           // 2*B*CT*G3*4 = 50,331,648 B
    u16*   x1  = (u16*)(ws + 50331648L);                 // B*T*1024*2  = 67,108,864 B
    float* h32 = (float*)(ws + 50331648L + 67108864L);   // 2*2*B*H*4   =    524,288 B
    u16*   wbf = (u16*)(ws + 50331648L + 67108864L + 524288L); // 14,155,776 B
    u16* wih0b = wbf;                      // 2*1536*256  =   786,432 el
    u16* wih1b = wbf + 786432L;            // 2*1536*1024 = 3,145,728 el
    u16* whh0b = wbf + 786432L + 3145728L; // 2*1536*512  = 1,572,864 el
    u16* whh1b = whh0b + 1572864L;         // 1,572,864 el

    // convert weights fp32 -> bf16 (graph-safe, runs every launch)
    k_cvt<<<512, 256, 0, stream>>>(wih0, wih0b, 786432);
    k_cvt<<<512, 256, 0, stream>>>(wih1, wih1b, 3145728);
    k_cvt<<<512, 256, 0, stream>>>(whh0, whh0b, 1572864);
    k_cvt<<<512, 256, 0, stream>>>(whh1, whh1b, 1572864);

    dim3 gg(32, 12, 2);   // 32 m-blocks(128 rows) x 12 n-tiles x 2 dirs
    dim3 gs(32, 2);       // 32 unit-tiles x 2 dirs

    // ---- layer 0 (embedding gather + fp32->bf16 fused into GEMM A-staging) ----
    k_zero<<<512, 256, 0, stream>>>(h32);
    for (int c = 0; c < T / CT; c++) {
        k_gemm_xg<<<gg, 256, 0, stream>>>(sent, emb, 1, wih0b, bih0, xg, E, c);
        for (int s = c * CT; s < (c + 1) * CT; s++)
            k_step<<<gs, 256, 0, stream>>>(whh0b, bhh0, xg, h32, s, x1, 1);
    }

    // ---- layer 1 (A = x1, already bf16) ----
    k_zero<<<512, 256, 0, stream>>>(h32);
    for (int c = 0; c < T / CT; c++) {
        k_gemm_xg<<<gg, 256, 0, stream>>>(sent, x1, 0, wih1b, bih1, xg, 2 * H, c);
        for (int s = c * CT; s < (c + 1) * CT; s++)
            k_step<<<gs, 256, 0, stream>>>(whh1b, bhh1, xg, h32, s, (u16*)nullptr, 0);
    }

    k_fc<<<B, 256, 0, stream>>>(h32, fcw, fcb, outp);
}

// Round 7
// 12665.372 us; speedup vs baseline: 44.6708x; 1.0809x over previous
//
#include <hip/hip_runtime.h>
#include <stdint.h>

#define H   512
#define B   64
#define T   512
#define E   256
#define G3  1536   // 3*H
#define CT  64     // time-chunk length (T/CT = 8 chunks)
#define NBD 32     // recurrence blocks per direction (16 units each)

typedef short s16;
typedef unsigned short u16;
typedef __attribute__((ext_vector_type(8))) short   short8;
typedef __attribute__((ext_vector_type(4))) float   f32x4;
typedef __bf16 bf8_t __attribute__((ext_vector_type(8)));

__device__ __forceinline__ u16 f2b(float f) {
    union { float f; unsigned int i; } v; v.f = f;
    unsigned int r = v.i + 0x7FFF + ((v.i >> 16) & 1);
    return (u16)(r >> 16);
}
__device__ __forceinline__ float sigm(float x)  { return 1.f / (1.f + __expf(-x)); }
__device__ __forceinline__ float tanhs(float x) { return 1.f - 2.f / (1.f + __expf(2.f * x)); }

// ------------------------------------------------------- fp32 -> bf16 weight convert
__global__ void k_cvt(const float* __restrict__ src, u16* __restrict__ dst, int n) {
    int i = blockIdx.x * 256 + threadIdx.x;
    int stride = gridDim.x * 256;
    for (; i < n; i += stride) dst[i] = f2b(src[i]);
}

// ------------------------------------------------------- init h32/hbf/bar
__global__ void k_init(float* __restrict__ h32, u16* __restrict__ hbf, int* __restrict__ bar) {
    int i = blockIdx.x * 256 + threadIdx.x;      // 131072 = 2 dirs * 2 slices * B*H
    h32[i] = 0.f;
    hbf[i] = 0;
    if (i < 64) bar[i] = 0;
}

// ------------------------------------------------------- xg chunk GEMM (MFMA)
// Writes xgT[d][tl][n][b] (fp32) = A[b,t,:K] . Wbf[d][n][:K] + bih[d][n]
// row m of the M=4096 tile: b=m>>6, tl=m&63; t = t0(d,c)+tl.
// A: layer0 = emb fp32 gathered via sent (aIsF32=1); layer1 = x1 bf16.
#define BM 128
#define BN 128
#define BK 32

__global__ __launch_bounds__(256)
void k_gemm_xg(const int* __restrict__ sent, const void* __restrict__ Abuf, int aIsF32,
               const u16* __restrict__ Wbf, const float* __restrict__ bih,
               float* __restrict__ xgT, int K, int c) {
    int d  = blockIdx.z;
    int t0 = d ? (T - (c + 1) * CT) : c * CT;
    const u16* Bw = Wbf + (long)d * G3 * K;
    const float* bias = bih + (long)d * G3;
    float* C = xgT + (long)d * (long)CT * G3 * B;

    __shared__ __align__(16) s16 lA[BM * BK];
    __shared__ __align__(16) s16 lB[BN * BK];

    int tid  = threadIdx.x;
    int lane = tid & 63;
    int wv   = tid >> 6;
    int wm   = wv >> 1, wn = wv & 1;
    int q    = lane >> 4, r16 = lane & 15;

    long m0 = (long)blockIdx.x * BM;
    long n0 = (long)blockIdx.y * BN;

    const float* rowAf[2];
    const s16*   rowAh[2];
    const u16*   rowB[2];
    #pragma unroll
    for (int i = 0; i < 2; i++) {
        int ch = tid + i * 256;
        int r  = ch >> 2, cc = (ch & 3) * 8;
        long m = m0 + r;
        int  bb_ = (int)(m >> 6), tl = (int)(m & 63);
        int  t  = t0 + tl;
        if (aIsF32) rowAf[i] = (const float*)Abuf + (long)sent[bb_ * T + t] * K + cc;
        else        rowAh[i] = (const s16*)Abuf + ((long)bb_ * T + t) * K + cc;
        rowB[i] = Bw + (n0 + r) * K + cc;
    }

    f32x4 acc[4][4];
    #pragma unroll
    for (int i = 0; i < 4; i++)
        #pragma unroll
        for (int j = 0; j < 4; j++) acc[i][j] = (f32x4){0.f, 0.f, 0.f, 0.f};

    for (long k0 = 0; k0 < K; k0 += BK) {
        #pragma unroll
        for (int i = 0; i < 2; i++) {
            if (aIsF32) {
                float4 v0 = *(const float4*)(rowAf[i] + k0);
                float4 v1 = *(const float4*)(rowAf[i] + k0 + 4);
                short8 pk;
                pk[0] = (s16)f2b(v0.x); pk[1] = (s16)f2b(v0.y);
                pk[2] = (s16)f2b(v0.z); pk[3] = (s16)f2b(v0.w);
                pk[4] = (s16)f2b(v1.x); pk[5] = (s16)f2b(v1.y);
                pk[6] = (s16)f2b(v1.z); pk[7] = (s16)f2b(v1.w);
                ((short8*)lA)[tid + i * 256] = pk;
            } else {
                ((short8*)lA)[tid + i * 256] = *(const short8*)(rowAh[i] + k0);
            }
            ((short8*)lB)[tid + i * 256] = *(const short8*)((const s16*)rowB[i] + k0);
        }
        __syncthreads();

        bf8_t af[4], bf[4];
        #pragma unroll
        for (int mt = 0; mt < 4; mt++)
            af[mt] = ((const bf8_t*)lA)[(wm * 64 + mt * 16 + r16) * 4 + q];
        #pragma unroll
        for (int nt = 0; nt < 4; nt++)
            bf[nt] = ((const bf8_t*)lB)[(wn * 64 + nt * 16 + r16) * 4 + q];
        #pragma unroll
        for (int mt = 0; mt < 4; mt++)
            #pragma unroll
            for (int nt = 0; nt < 4; nt++)
                acc[mt][nt] = __builtin_amdgcn_mfma_f32_16x16x32_bf16(
                                  af[mt], bf[nt], acc[mt][nt], 0, 0, 0);
        __syncthreads();
    }

    // D[m][n]: n = lane&15 (+tiles), m = (lane>>4)*4+reg (+tiles); scatter to [tl][n][b]
    #pragma unroll
    for (int nt = 0; nt < 4; nt++) {
        long n = n0 + wn * 64 + nt * 16 + r16;
        float bv = bias[n];
        #pragma unroll
        for (int mt = 0; mt < 4; mt++) {
            #pragma unroll
            for (int rg = 0; rg < 4; rg++) {
                long m = m0 + wm * 64 + mt * 16 + q * 4 + rg;
                C[((long)(m & 63) * G3 + n) * B + (m >> 6)] = acc[mt][nt][rg] + bv;
            }
        }
    }
}

// ------------------------------------------------------- persistent chunk recurrence
// grid (NBD=32, 2 dirs) x 256 thr. Block owns 16 units; wave g owns batches g*16..+15.
// 64 steps internally; device-scope atomic grid barrier per step (per-dir counters).
// Weights as 48 register B-frags; h: fp32 (epilogue) + bf16 shadow (MFMA A-operand).
__global__ __launch_bounds__(256, 1)
void k_chunk(const u16* __restrict__ Whhbf, const float* __restrict__ bhh,
             const float* __restrict__ xgT, float* __restrict__ h32,
             u16* __restrict__ hbf, int c, u16* __restrict__ x1out, int writeX1,
             int* __restrict__ bar) {
    int u0  = blockIdx.x * 16;
    int d   = blockIdx.y;
    int lane = threadIdx.x & 63;
    int g    = threadIdx.x >> 6;
    int q    = lane >> 4, cc = lane & 15;
    int u    = u0 + cc;

    const u16* W  = Whhbf + (long)d * G3 * H;
    const float* bb = bhh + (long)d * G3;
    const float* xgf = xgT + (long)d * (long)CT * G3 * B;
    float* h32d = h32 + (long)d * 2 * B * H;
    u16*   hbfd = hbf + (long)d * 2 * B * H;
    int*   barp = bar + d * 16;                   // separate cachelines per dir

    // B-fragments (weights) in registers: 3 gates x 16 kc = 192 VGPRs
    bf8_t wf[3][16];
    #pragma unroll
    for (int gate = 0; gate < 3; gate++)
        #pragma unroll
        for (int kc = 0; kc < 16; kc++)
            wf[gate][kc] = *(const bf8_t*)(W + (long)(gate * H + u) * H + kc * 32 + q * 8);

    float br = bb[u], bz = bb[H + u], bn = bb[2 * H + u];
    int base = c * CT;

    for (int sl = 0; sl < CT; sl++) {
        int s    = base + sl;
        int tl   = d ? (CT - 1 - sl) : sl;
        int time = d ? (T - 1 - s) : s;
        const u16*   hpb = hbfd + (long)(s & 1) * B * H;
        const float* hpf = h32d + (long)(s & 1) * B * H;
        float* hnf = h32d + (long)((s + 1) & 1) * B * H;
        u16*   hnb = hbfd + (long)((s + 1) & 1) * B * H;

        f32x4 aR = (f32x4){0.f,0.f,0.f,0.f};
        f32x4 aZ = (f32x4){0.f,0.f,0.f,0.f};
        f32x4 aN = (f32x4){0.f,0.f,0.f,0.f};

        const u16* hrow = hpb + (long)(g * 16 + cc) * H;
        #pragma unroll
        for (int kc = 0; kc < 16; kc++) {
            bf8_t af = *(const bf8_t*)(hrow + kc * 32 + q * 8);
            aR = __builtin_amdgcn_mfma_f32_16x16x32_bf16(af, wf[0][kc], aR, 0, 0, 0);
            aZ = __builtin_amdgcn_mfma_f32_16x16x32_bf16(af, wf[1][kc], aZ, 0, 0, 0);
            aN = __builtin_amdgcn_mfma_f32_16x16x32_bf16(af, wf[2][kc], aN, 0, 0, 0);
        }

        #pragma unroll
        for (int rg = 0; rg < 4; rg++) {
            int b = g * 16 + q * 4 + rg;          // D layout: m = (lane>>4)*4+reg
            long xb = ((long)tl * G3 + u) * B + b;
            float r = sigm(xgf[xb]                 + aR[rg] + br);
            float z = sigm(xgf[xb + (long)H * B]   + aZ[rg] + bz);
            float n = tanhs(xgf[xb + (long)2*H*B]  + r * (aN[rg] + bn));
            float hp = hpf[(long)b * H + u];
            float hh = (1.f - z) * n + z * hp;
            hnf[(long)b * H + u] = hh;
            hnb[(long)b * H + u] = f2b(hh);
            if (writeX1)
                x1out[((long)b * T + time) * 1024 + d * H + u] = f2b(hh);
        }

        // ---- device-scope grid barrier over this dir's 32 blocks ----
        __syncthreads();                          // drains each wave's stores (vmcnt 0)
        if (threadIdx.x == 0) {
            __builtin_amdgcn_fence(__ATOMIC_RELEASE, "agent");
            __hip_atomic_fetch_add(barp, 1, __ATOMIC_RELAXED, __HIP_MEMORY_SCOPE_AGENT);
            int target = NBD * (base + sl + 1);   // monotonic across chunks of a layer
            while (__hip_atomic_load(barp, __ATOMIC_RELAXED, __HIP_MEMORY_SCOPE_AGENT) < target)
                __builtin_amdgcn_s_sleep(1);
            __builtin_amdgcn_fence(__ATOMIC_ACQUIRE, "agent");
        }
        __syncthreads();
    }
}

// ------------------------------------------------------- final FC (fp32)
__global__ __launch_bounds__(256)
void k_fc(const float* __restrict__ h32, const float* __restrict__ fcw,
          const float* __restrict__ fcb, float* __restrict__ out) {
    int b   = blockIdx.x;
    int tid = threadIdx.x;
    float p[10];
    #pragma unroll
    for (int o = 0; o < 10; o++) p[o] = 0.f;
    for (int k = tid; k < 1024; k += 256) {
        int dd = k >> 9, kk = k & 511;
        // final h lives in ping-pong slice 0 of each dir (T even)
        float hv = h32[(long)dd * 2 * B * H + (long)b * H + kk];
        #pragma unroll
        for (int o = 0; o < 10; o++) p[o] += hv * fcw[o * 1024 + k];
    }
    __shared__ float red[10][256];
    #pragma unroll
    for (int o = 0; o < 10; o++) red[o][tid] = p[o];
    __syncthreads();
    for (int off = 128; off > 0; off >>= 1) {
        if (tid < off)
            #pragma unroll
            for (int o = 0; o < 10; o++) red[o][tid] += red[o][tid + off];
        __syncthreads();
    }
    if (tid < 10) out[b * 10 + tid] = red[tid][0] + fcb[tid];
}

// ------------------------------------------------------- launcher
extern "C" void kernel_launch(void* const* d_in, const int* in_sizes, int n_in,
                              void* d_out, int out_size, void* d_ws, size_t ws_size,
                              hipStream_t stream) {
    const int*   sent = (const int*)d_in[0];
    const float* emb  = (const float*)d_in[1];
    const float* wih0 = (const float*)d_in[2];
    const float* whh0 = (const float*)d_in[3];
    const float* bih0 = (const float*)d_in[4];
    const float* bhh0 = (const float*)d_in[5];
    const float* wih1 = (const float*)d_in[6];
    const float* whh1 = (const float*)d_in[7];
    const float* bih1 = (const float*)d_in[8];
    const float* bhh1 = (const float*)d_in[9];
    const float* fcw  = (const float*)d_in[10];
    const float* fcb  = (const float*)d_in[11];
    float* outp = (float*)d_out;

    // workspace layout — ~132.4 MB (proven-safe envelope: >=134.5 MB)
    char*  ws  = (char*)d_ws;
    float* xg  = (float*)(ws);                           // 2*CT*G3*B*4 = 50,331,648 B
    u16*   x1  = (u16*)(ws + 50331648L);                 // B*T*1024*2  = 67,108,864 B
    float* h32 = (float*)(ws + 50331648L + 67108864L);   // 2*2*B*H*4   =    524,288 B
    u16*   hbf = (u16*)(ws + 50331648L + 67108864L + 524288L);   // 262,144 B
    int*   bar = (int*)(ws + 50331648L + 67108864L + 524288L + 262144L); // 256 B
    u16*   wbf = (u16*)(ws + 50331648L + 67108864L + 524288L + 262144L + 256L);
    u16* wih0b = wbf;                      // 2*1536*256  =   786,432 el
    u16* wih1b = wbf + 786432L;            // 2*1536*1024 = 3,145,728 el
    u16* whh0b = wbf + 786432L + 3145728L; // 2*1536*512  = 1,572,864 el
    u16* whh1b = whh0b + 1572864L;         // 1,572,864 el

    // convert weights fp32 -> bf16 (graph-safe, runs every launch)
    k_cvt<<<512, 256, 0, stream>>>(wih0, wih0b, 786432);
    k_cvt<<<512, 256, 0, stream>>>(wih1, wih1b, 3145728);
    k_cvt<<<512, 256, 0, stream>>>(whh0, whh0b, 1572864);
    k_cvt<<<512, 256, 0, stream>>>(whh1, whh1b, 1572864);

    dim3 gg(32, 12, 2);    // GEMM: 32 m-blocks x 12 n-tiles x 2 dirs
    dim3 gc(NBD, 2);       // recurrence: 32 unit-tiles x 2 dirs (64 blocks, co-resident)

    // ---- layer 0 (embedding gather fused into GEMM A-staging) ----
    k_init<<<512, 256, 0, stream>>>(h32, hbf, bar);
    for (int c = 0; c < T / CT; c++) {
        k_gemm_xg<<<gg, 256, 0, stream>>>(sent, emb, 1, wih0b, bih0, xg, E, c);
        k_chunk<<<gc, 256, 0, stream>>>(whh0b, bhh0, xg, h32, hbf, c, x1, 1, bar);
    }

    // ---- layer 1 (A = x1, already bf16) ----
    k_init<<<512, 256, 0, stream>>>(h32, hbf, bar);
    for (int c = 0; c < T / CT; c++) {
        k_gemm_xg<<<gg, 256, 0, stream>>>(sent, x1, 0, wih1b, bih1, xg, 2 * H, c);
        k_chunk<<<gc, 256, 0, stream>>>(whh1b, bhh1, xg, h32, hbf, c, (u16*)nullptr, 0, bar);
    }

    k_fc<<<B, 256, 0, stream>>>(h32, fcw, fcb, outp);
}

// Round 10
// 7286.572 us; speedup vs baseline: 77.6459x; 1.7382x over previous
//
#include <hip/hip_runtime.h>
#include <stdint.h>

#define H   512
#define B   64
#define T   512
#define E   256
#define G3  1536   // 3*H
#define CT  64     // time-chunk length (T/CT = 8 chunks)
#define NBD 32     // recurrence blocks per direction (16 units each)

typedef short s16;
typedef unsigned short u16;
typedef __attribute__((ext_vector_type(8))) short   short8;
typedef __attribute__((ext_vector_type(4))) float   f32x4;
typedef __attribute__((ext_vector_type(4))) unsigned int u32x4;
typedef __bf16 bf8_t __attribute__((ext_vector_type(8)));

__device__ __forceinline__ u16 f2b(float f) {
    union { float f; unsigned int i; } v; v.f = f;
    unsigned int r = v.i + 0x7FFF + ((v.i >> 16) & 1);
    return (u16)(r >> 16);
}
__device__ __forceinline__ float sigm(float x)  { return 1.f / (1.f + __expf(-x)); }
__device__ __forceinline__ float tanhs(float x) { return 1.f - 2.f / (1.f + __expf(2.f * x)); }

// ------------------------------------------------------- fp32 -> bf16 weight convert
__global__ void k_cvt(const float* __restrict__ src, u16* __restrict__ dst, int n) {
    int i = blockIdx.x * 256 + threadIdx.x;
    int stride = gridDim.x * 256;
    for (; i < n; i += stride) dst[i] = f2b(src[i]);
}

// ------------------------------------------------------- init h32/hbf/bar
__global__ void k_init(float* __restrict__ h32, u16* __restrict__ hbf, int* __restrict__ bar) {
    int i = blockIdx.x * 256 + threadIdx.x;      // 131072 = 2 dirs * 2 slices * B*H
    hbf[i] = 0;
    if (i < 65536) h32[i] = 0.f;                 // 2 dirs * B*H carry
    if (i < 64)    bar[i] = 0;
}

// ------------------------------------------------------- xg chunk GEMM (MFMA)
// Writes xgT[d][tl][n][b] (fp32) = A[b,t,:K] . Wbf[d][n][:K] + bih[d][n]
// row m of the M=4096 tile: b=m>>6, tl=m&63; t = t0(d,c)+tl.
#define BM 128
#define BN 128
#define BK 32

__global__ __launch_bounds__(256)
void k_gemm_xg(const int* __restrict__ sent, const void* __restrict__ Abuf, int aIsF32,
               const u16* __restrict__ Wbf, const float* __restrict__ bih,
               float* __restrict__ xgT, int K, int c) {
    int d  = blockIdx.z;
    int t0 = d ? (T - (c + 1) * CT) : c * CT;
    const u16* Bw = Wbf + (long)d * G3 * K;
    const float* bias = bih + (long)d * G3;
    float* C = xgT + (long)d * (long)CT * G3 * B;

    __shared__ __align__(16) s16 lA[BM * BK];
    __shared__ __align__(16) s16 lB[BN * BK];

    int tid  = threadIdx.x;
    int lane = tid & 63;
    int wv   = tid >> 6;
    int wm   = wv >> 1, wn = wv & 1;
    int q    = lane >> 4, r16 = lane & 15;

    long m0 = (long)blockIdx.x * BM;
    long n0 = (long)blockIdx.y * BN;

    const float* rowAf[2];
    const s16*   rowAh[2];
    const u16*   rowB[2];
    #pragma unroll
    for (int i = 0; i < 2; i++) {
        int ch = tid + i * 256;
        int r  = ch >> 2, cc = (ch & 3) * 8;
        long m = m0 + r;
        int  bb_ = (int)(m >> 6), tl = (int)(m & 63);
        int  t  = t0 + tl;
        if (aIsF32) rowAf[i] = (const float*)Abuf + (long)sent[bb_ * T + t] * K + cc;
        else        rowAh[i] = (const s16*)Abuf + ((long)bb_ * T + t) * K + cc;
        rowB[i] = Bw + (n0 + r) * K + cc;
    }

    f32x4 acc[4][4];
    #pragma unroll
    for (int i = 0; i < 4; i++)
        #pragma unroll
        for (int j = 0; j < 4; j++) acc[i][j] = (f32x4){0.f, 0.f, 0.f, 0.f};

    for (long k0 = 0; k0 < K; k0 += BK) {
        #pragma unroll
        for (int i = 0; i < 2; i++) {
            if (aIsF32) {
                float4 v0 = *(const float4*)(rowAf[i] + k0);
                float4 v1 = *(const float4*)(rowAf[i] + k0 + 4);
                short8 pk;
                pk[0] = (s16)f2b(v0.x); pk[1] = (s16)f2b(v0.y);
                pk[2] = (s16)f2b(v0.z); pk[3] = (s16)f2b(v0.w);
                pk[4] = (s16)f2b(v1.x); pk[5] = (s16)f2b(v1.y);
                pk[6] = (s16)f2b(v1.z); pk[7] = (s16)f2b(v1.w);
                ((short8*)lA)[tid + i * 256] = pk;
            } else {
                ((short8*)lA)[tid + i * 256] = *(const short8*)(rowAh[i] + k0);
            }
            ((short8*)lB)[tid + i * 256] = *(const short8*)((const s16*)rowB[i] + k0);
        }
        __syncthreads();

        bf8_t af[4], bf[4];
        #pragma unroll
        for (int mt = 0; mt < 4; mt++)
            af[mt] = ((const bf8_t*)lA)[(wm * 64 + mt * 16 + r16) * 4 + q];
        #pragma unroll
        for (int nt = 0; nt < 4; nt++)
            bf[nt] = ((const bf8_t*)lB)[(wn * 64 + nt * 16 + r16) * 4 + q];
        #pragma unroll
        for (int mt = 0; mt < 4; mt++)
            #pragma unroll
            for (int nt = 0; nt < 4; nt++)
                acc[mt][nt] = __builtin_amdgcn_mfma_f32_16x16x32_bf16(
                                  af[mt], bf[nt], acc[mt][nt], 0, 0, 0);
        __syncthreads();
    }

    #pragma unroll
    for (int nt = 0; nt < 4; nt++) {
        long n = n0 + wn * 64 + nt * 16 + r16;
        float bv = bias[n];
        #pragma unroll
        for (int mt = 0; mt < 4; mt++) {
            #pragma unroll
            for (int rg = 0; rg < 4; rg++) {
                long m = m0 + wm * 64 + mt * 16 + q * 4 + rg;
                C[((long)(m & 63) * G3 + n) * B + (m >> 6)] = acc[mt][nt][rg] + bv;
            }
        }
    }
}

// ------------------------------------------------------- persistent chunk recurrence
// grid (NBD=32, 2 dirs) x 256 thr. Block owns 16 units; wave g owns batches g*16..+15.
// Weights staged once in LDS (48 KB); per-step B-frags via ds_read_b128.
// Cross-block h state (hbf) via write-through (sc0 sc1) stores + one monolithic
// cache-bypass load block (16 loads + internal s_waitcnt, early-clobber outputs).
// Fence-free relaxed-atomic grid barrier. fp32 h-carry in registers.
__global__ __launch_bounds__(256, 1)
void k_chunk(const u16* __restrict__ Whhbf, const float* __restrict__ bhh,
             const float* __restrict__ xgT, float* __restrict__ h32,
             u16* __restrict__ hbf, int c, u16* __restrict__ x1out, int writeX1,
             int* __restrict__ bar) {
    int u0  = blockIdx.x * 16;
    int d   = blockIdx.y;
    int lane = threadIdx.x & 63;
    int g    = threadIdx.x >> 6;
    int q    = lane >> 4, cc = lane & 15;
    int u    = u0 + cc;

    const u16* W  = Whhbf + (long)d * G3 * H;
    const float* bb = bhh + (long)d * G3;
    const float* xgf = xgT + (long)d * (long)CT * G3 * B;
    float* h32d = h32 + (long)d * B * H;
    u16*   hbfd = hbf + (long)d * 2 * B * H;
    int*   barp = bar + d * 32;                   // 128 B apart per dir

    // ---- stage this block's weights into LDS: [gate][kc][lane] 16B frags ----
    __shared__ __align__(16) u16 lw[3 * 16 * 64 * 8];   // 49152 B
    for (int f = threadIdx.x; f < 3072; f += 256) {
        int gate = f >> 10;
        int rem  = f & 1023;
        int kc   = rem >> 6;
        int ln   = rem & 63;
        int qq   = ln >> 4, c2 = ln & 15;
        *(short8*)(lw + (long)f * 8) =
            *(const short8*)(W + (long)(gate * H + u0 + c2) * H + kc * 32 + qq * 8);
    }
    __syncthreads();
    const bf8_t* lwf = (const bf8_t*)lw;          // index: (gate*16+kc)*64 + lane

    float br = bb[u], bz = bb[H + u], bn = bb[2 * H + u];

    // fp32 h-carry (wave-private): lane holds h[b=g*16+q*4+rg][u]
    float hp[4];
    #pragma unroll
    for (int rg = 0; rg < 4; rg++)
        hp[rg] = h32d[(long)(g * 16 + q * 4 + rg) * H + u];

    int base = c * CT;
    int bA = g * 16 + cc;                         // A-frag row (m = lane&15)

    for (int sl = 0; sl < CT; sl++) {
        int s    = base + sl;
        int tl   = d ? (CT - 1 - sl) : sl;
        int time = d ? (T - 1 - s) : s;

        // xg loads (normal cached; overlap the hbf fetch latency)
        float xr[4], xz[4], xn[4];
        #pragma unroll
        for (int rg = 0; rg < 4; rg++) {
            long xb = ((long)tl * G3 + u) * B + (g * 16 + q * 4 + rg);
            xr[rg] = xgf[xb];
            xz[rg] = xgf[xb + (long)H * B];
            xn[rg] = xgf[xb + (long)2 * H * B];
        }

        // A-fragments: one monolithic bypass-load block.
        // Early-clobber outputs (no overlap with %16 address) + internal waitcnt
        // (results valid at asm end — nothing can be scheduled in between).
        const u16* hq = hbfd + (long)(s & 1) * B * H + (long)bA * H + q * 8;
        u32x4 a0,a1,a2,a3,a4,a5,a6,a7,a8,a9,a10,a11,a12,a13,a14,a15;
        asm volatile(
            "global_load_dwordx4 %0,  %16, off sc0 sc1\n\t"
            "global_load_dwordx4 %1,  %16, off offset:64  sc0 sc1\n\t"
            "global_load_dwordx4 %2,  %16, off offset:128 sc0 sc1\n\t"
            "global_load_dwordx4 %3,  %16, off offset:192 sc0 sc1\n\t"
            "global_load_dwordx4 %4,  %16, off offset:256 sc0 sc1\n\t"
            "global_load_dwordx4 %5,  %16, off offset:320 sc0 sc1\n\t"
            "global_load_dwordx4 %6,  %16, off offset:384 sc0 sc1\n\t"
            "global_load_dwordx4 %7,  %16, off offset:448 sc0 sc1\n\t"
            "global_load_dwordx4 %8,  %16, off offset:512 sc0 sc1\n\t"
            "global_load_dwordx4 %9,  %16, off offset:576 sc0 sc1\n\t"
            "global_load_dwordx4 %10, %16, off offset:640 sc0 sc1\n\t"
            "global_load_dwordx4 %11, %16, off offset:704 sc0 sc1\n\t"
            "global_load_dwordx4 %12, %16, off offset:768 sc0 sc1\n\t"
            "global_load_dwordx4 %13, %16, off offset:832 sc0 sc1\n\t"
            "global_load_dwordx4 %14, %16, off offset:896 sc0 sc1\n\t"
            "global_load_dwordx4 %15, %16, off offset:960 sc0 sc1\n\t"
            "s_waitcnt vmcnt(0)"
            : "=&v"(a0),"=&v"(a1),"=&v"(a2),"=&v"(a3),
              "=&v"(a4),"=&v"(a5),"=&v"(a6),"=&v"(a7),
              "=&v"(a8),"=&v"(a9),"=&v"(a10),"=&v"(a11),
              "=&v"(a12),"=&v"(a13),"=&v"(a14),"=&v"(a15)
            : "v"(hq)
            : "memory");
        bf8_t af[16];
        af[0]=__builtin_bit_cast(bf8_t,a0);   af[1]=__builtin_bit_cast(bf8_t,a1);
        af[2]=__builtin_bit_cast(bf8_t,a2);   af[3]=__builtin_bit_cast(bf8_t,a3);
        af[4]=__builtin_bit_cast(bf8_t,a4);   af[5]=__builtin_bit_cast(bf8_t,a5);
        af[6]=__builtin_bit_cast(bf8_t,a6);   af[7]=__builtin_bit_cast(bf8_t,a7);
        af[8]=__builtin_bit_cast(bf8_t,a8);   af[9]=__builtin_bit_cast(bf8_t,a9);
        af[10]=__builtin_bit_cast(bf8_t,a10); af[11]=__builtin_bit_cast(bf8_t,a11);
        af[12]=__builtin_bit_cast(bf8_t,a12); af[13]=__builtin_bit_cast(bf8_t,a13);
        af[14]=__builtin_bit_cast(bf8_t,a14); af[15]=__builtin_bit_cast(bf8_t,a15);

        f32x4 aR = (f32x4){0.f,0.f,0.f,0.f};
        f32x4 aZ = (f32x4){0.f,0.f,0.f,0.f};
        f32x4 aN = (f32x4){0.f,0.f,0.f,0.f};
        #pragma unroll
        for (int kc = 0; kc < 16; kc++) {
            aR = __builtin_amdgcn_mfma_f32_16x16x32_bf16(af[kc], lwf[(0*16+kc)*64 + lane], aR, 0, 0, 0);
            aZ = __builtin_amdgcn_mfma_f32_16x16x32_bf16(af[kc], lwf[(1*16+kc)*64 + lane], aZ, 0, 0, 0);
            aN = __builtin_amdgcn_mfma_f32_16x16x32_bf16(af[kc], lwf[(2*16+kc)*64 + lane], aN, 0, 0, 0);
        }

        u16* hnb = hbfd + (long)((s + 1) & 1) * B * H;
        #pragma unroll
        for (int rg = 0; rg < 4; rg++) {
            int b = g * 16 + q * 4 + rg;          // D layout: m = (lane>>4)*4+reg
            float r = sigm(xr[rg] + aR[rg] + br);
            float z = sigm(xz[rg] + aZ[rg] + bz);
            float n = tanhs(xn[rg] + r * (aN[rg] + bn));
            float hh = (1.f - z) * n + z * hp[rg];
            hp[rg] = hh;
            u16 hv = f2b(hh);
            // write-through store: visible at device coherence point after vmcnt ack
            asm volatile("global_store_short %0, %1, off sc0 sc1"
                         :: "v"(hnb + (long)b * H + u), "v"((unsigned int)hv) : "memory");
            if (writeX1)
                x1out[((long)b * T + time) * 1024 + d * H + u] = hv;
        }

        // drain this wave's stores, then barrier (relaxed agent atomics, no fences)
        asm volatile("s_waitcnt vmcnt(0)" ::: "memory");
        __syncthreads();
        if (threadIdx.x == 0) {
            __hip_atomic_fetch_add(barp, 1, __ATOMIC_RELAXED, __HIP_MEMORY_SCOPE_AGENT);
            int target = NBD * (base + sl + 1);   // monotonic across chunks of a layer
            while (__hip_atomic_load(barp, __ATOMIC_RELAXED, __HIP_MEMORY_SCOPE_AGENT) < target)
                __builtin_amdgcn_s_sleep(1);
        }
        __syncthreads();
    }

    // spill fp32 carry for next chunk dispatch / k_fc (kernel-boundary coherence)
    #pragma unroll
    for (int rg = 0; rg < 4; rg++)
        h32d[(long)(g * 16 + q * 4 + rg) * H + u] = hp[rg];
}

// ------------------------------------------------------- final FC (fp32)
__global__ __launch_bounds__(256)
void k_fc(const float* __restrict__ h32, const float* __restrict__ fcw,
          const float* __restrict__ fcb, float* __restrict__ out) {
    int b   = blockIdx.x;
    int tid = threadIdx.x;
    float p[10];
    #pragma unroll
    for (int o = 0; o < 10; o++) p[o] = 0.f;
    for (int k = tid; k < 1024; k += 256) {
        int dd = k >> 9, kk = k & 511;
        float hv = h32[(long)dd * B * H + (long)b * H + kk];
        #pragma unroll
        for (int o = 0; o < 10; o++) p[o] += hv * fcw[o * 1024 + k];
    }
    __shared__ float red[10][256];
    #pragma unroll
    for (int o = 0; o < 10; o++) red[o][tid] = p[o];
    __syncthreads();
    for (int off = 128; off > 0; off >>= 1) {
        if (tid < off)
            #pragma unroll
            for (int o = 0; o < 10; o++) red[o][tid] += red[o][tid + off];
        __syncthreads();
    }
    if (tid < 10) out[b * 10 + tid] = red[tid][0] + fcb[tid];
}

// ------------------------------------------------------- launcher
extern "C" void kernel_launch(void* const* d_in, const int* in_sizes, int n_in,
                              void* d_out, int out_size, void* d_ws, size_t ws_size,
                              hipStream_t stream) {
    const int*   sent = (const int*)d_in[0];
    const float* emb  = (const float*)d_in[1];
    const float* wih0 = (const float*)d_in[2];
    const float* whh0 = (const float*)d_in[3];
    const float* bih0 = (const float*)d_in[4];
    const float* bhh0 = (const float*)d_in[5];
    const float* wih1 = (const float*)d_in[6];
    const float* whh1 = (const float*)d_in[7];
    const float* bih1 = (const float*)d_in[8];
    const float* bhh1 = (const float*)d_in[9];
    const float* fcw  = (const float*)d_in[10];
    const float* fcb  = (const float*)d_in[11];
    float* outp = (float*)d_out;

    // workspace layout — ~132.1 MB (proven-safe envelope: >=134.5 MB)
    char*  ws  = (char*)d_ws;
    float* xg  = (float*)(ws);                           // 2*CT*G3*B*4 = 50,331,648 B
    u16*   x1  = (u16*)(ws + 50331648L);                 // B*T*1024*2  = 67,108,864 B
    float* h32 = (float*)(ws + 50331648L + 67108864L);   // 2*B*H*4     =    262,144 B
    u16*   hbf = (u16*)(ws + 50331648L + 67108864L + 262144L);   // 262,144 B
    int*   bar = (int*)(ws + 50331648L + 67108864L + 262144L + 262144L); // 256 B
    u16*   wbf = (u16*)(ws + 50331648L + 67108864L + 262144L + 262144L + 256L);
    u16* wih0b = wbf;                      // 2*1536*256  =   786,432 el
    u16* wih1b = wbf + 786432L;            // 2*1536*1024 = 3,145,728 el
    u16* whh0b = wbf + 786432L + 3145728L; // 2*1536*512  = 1,572,864 el
    u16* whh1b = whh0b + 1572864L;         // 1,572,864 el

    // convert weights fp32 -> bf16 (graph-safe, runs every launch)
    k_cvt<<<512, 256, 0, stream>>>(wih0, wih0b, 786432);
    k_cvt<<<512, 256, 0, stream>>>(wih1, wih1b, 3145728);
    k_cvt<<<512, 256, 0, stream>>>(whh0, whh0b, 1572864);
    k_cvt<<<512, 256, 0, stream>>>(whh1, whh1b, 1572864);

    dim3 gg(32, 12, 2);    // GEMM: 32 m-blocks x 12 n-tiles x 2 dirs
    dim3 gc(NBD, 2);       // recurrence: 32 unit-tiles x 2 dirs (64 blocks, co-resident)

    // ---- layer 0 (embedding gather fused into GEMM A-staging) ----
    k_init<<<512, 256, 0, stream>>>(h32, hbf, bar);
    for (int c = 0; c < T / CT; c++) {
        k_gemm_xg<<<gg, 256, 0, stream>>>(sent, emb, 1, wih0b, bih0, xg, E, c);
        k_chunk<<<gc, 256, 0, stream>>>(whh0b, bhh0, xg, h32, hbf, c, x1, 1, bar);
    }

    // ---- layer 1 (A = x1, already bf16) ----
    k_init<<<512, 256, 0, stream>>>(h32, hbf, bar);
    for (int c = 0; c < T / CT; c++) {
        k_gemm_xg<<<gg, 256, 0, stream>>>(sent, x1, 0, wih1b, bih1, xg, 2 * H, c);
        k_chunk<<<gc, 256, 0, stream>>>(whh1b, bhh1, xg, h32, hbf, c, (u16*)nullptr, 0, bar);
    }

    k_fc<<<B, 256, 0, stream>>>(h32, fcw, fcb, outp);
}